// Round 2
// baseline (407.323 us; speedup 1.0000x reference)
//
#include <hip/hip_runtime.h>

// Pipeline (see reference):
//   bins = clip(|x|,0,20)  -> one-hot conv == per-pixel gather of w0[o, bin(tap), k]
//   stage1 kernel: fused layer0 (dil-8 3x3, BN0 folded) + layer1 (1x1 64->4, BN1 folded)
//                  + block rearrange (x qtable) + 1x1 512->3 (+b2, BN2 folded)
//                  -> z [8,3,64,64] f32 in d_ws (393,216 bytes)
//   stage2 kernel: bilinear x8 upsample (half-pixel centers, edge clamp) -> d_out
//
// R2: table layout [k][bin][o] with row stride 65 floats:
//   - 9 data-dependent LDS base addrs computed ONCE per 8x8 block; the o-loop
//     uses ds_read immediate offsets (o*4 <= 252) -> no inner-loop addressing VALU.
//   - stride 65 == 1 (mod 32): distinct bins -> distinct banks; equal bins ->
//     same-address broadcast. Conflict-free.
//   - grid 512 -> 2048 (t-loop split 4-way): 3 resident blocks/CU (LDS-capped)
//     instead of grid-capped 2.

#define NB_BINS 22   // 21 real bins + sentinel bin 21 for out-of-bounds taps
#define OSTRIDE 65   // 64 channels + 1 pad float (bank spread)

__global__ __launch_bounds__(256, 3) void dct_stage1(
    const int* __restrict__ xin,      // [8,1,512,512] int32
    const float* __restrict__ qtable, // [8,8,8]
    const float* __restrict__ w0,     // [64,21,3,3]
    const float* __restrict__ b0,     // [64]
    const float* __restrict__ s0,     // [64]
    const float* __restrict__ t0,     // [64]
    const float* __restrict__ w1,     // [4,64]
    const float* __restrict__ s1,     // [4]
    const float* __restrict__ t1,     // [4]
    const float* __restrict__ w2,     // [3,512]
    const float* __restrict__ b2,     // [3]
    const float* __restrict__ s2,     // [3]
    const float* __restrict__ t2,     // [3]
    float* __restrict__ zout)         // [8,3,64,64]
{
    // tab[k][bin][o] = s0[o]*w0[o][bin][ky][kx] + g0[o]/9   (bin < 21)
    //               = g0[o]/9                               (bin == 21, OOB tap)
    // where g0 = s0*b0 + t0.  Sum over the 9 taps then equals s0*conv + g0 exactly.
    __shared__ float tab[9 * NB_BINS * OSTRIDE];  // 51480 B
    __shared__ float w1s[64 * 4];                 // s1-folded w1, layout [o][c]

    const int tid = threadIdx.x;
    const int bid = blockIdx.x;       // 2048 workgroups: (b, hb, seg)
    const int b   = bid >> 8;
    const int hb  = (bid >> 2) & 63;
    const int seg = bid & 3;

    for (int t = tid; t < 9 * NB_BINS * 64; t += 256) {
        int kb = t >> 6;              // k*22 + bin
        int o  = t & 63;
        int k   = kb / NB_BINS;
        int bin = kb - k * NB_BINS;
        float g0 = fmaf(s0[o], b0[o], t0[o]) * (1.0f / 9.0f);
        float val = g0;
        if (bin < 21) {
            int ky = k / 3, kx = k - ky * 3;
            val = fmaf(s0[o], w0[((o * 21 + bin) * 3 + ky) * 3 + kx], g0);
        }
        tab[kb * OSTRIDE + o] = val;
    }
    for (int t = tid; t < 256; t += 256) {
        int o = t >> 2, c = t & 3;
        w1s[t] = s1[c] * w1[c * 64 + o];
    }
    __syncthreads();

    const int lane = tid & 63;
    const int wave = tid >> 6;
    const int i = lane >> 3;          // row within 8x8 block
    const int j = lane & 7;           // col within 8x8 block

    // Per-lane constants for the block-rearrange + 512->3 conv.
    // z channel index = c*64 + i*8 + j  (= c*64 + lane); channels 256.. get *qtable.
    const float q = qtable[b * 64 + lane];
    float A[3][4], Bq[3][4];
#pragma unroll
    for (int oc = 0; oc < 3; ++oc) {
        float s = s2[oc];
#pragma unroll
        for (int c = 0; c < 4; ++c) {
            A[oc][c]  = s * w2[oc * 512 + c * 64 + lane];
            Bq[oc][c] = s * w2[oc * 512 + 256 + c * 64 + lane];
        }
    }
    const float zc0 = fmaf(s2[0], b2[0], t2[0]);
    const float zc1 = fmaf(s2[1], b2[1], t2[1]);
    const float zc2 = fmaf(s2[2], b2[2], t2[2]);
    const float t1r0 = t1[0], t1r1 = t1[1], t1r2 = t1[2], t1r3 = t1[3];

    const int y = hb * 8 + i;

    for (int t = 0; t < 4; ++t) {
        const int wb = wave * 16 + seg * 4 + t;   // 4 waves x (4 segs x 4) -> 64 blocks
        const int xc = wb * 8 + j;

        // 9 tap bins -> LDS row base pointers (k*22 + bin) * OSTRIDE
        const float* bp[9];
#pragma unroll
        for (int ky = 0; ky < 3; ++ky) {
#pragma unroll
            for (int kx = 0; kx < 3; ++kx) {
                int yy = y + (ky - 1) * 8;
                int xx = xc + (kx - 1) * 8;
                int bin = 21;
                if ((unsigned)yy < 512u && (unsigned)xx < 512u) {
                    int v = xin[(b * 512 + yy) * 512 + xx];
                    v = v < 0 ? -v : v;
                    bin = v > 20 ? 20 : v;
                }
                bp[ky * 3 + kx] = &tab[((ky * 3 + kx) * NB_BINS + bin) * OSTRIDE];
            }
        }

        float u0 = t1r0, u1 = t1r1, u2 = t1r2, u3 = t1r3;
#pragma unroll
        for (int o = 0; o < 64; ++o) {
            float acc = bp[0][o] + bp[1][o] + bp[2][o]
                      + bp[3][o] + bp[4][o] + bp[5][o]
                      + bp[6][o] + bp[7][o] + bp[8][o];
            float v = fmaxf(acc, 0.0f);   // relu(s0*conv0 + s0*b0 + t0)
            const float4 w = *(const float4*)&w1s[o * 4];
            u0 = fmaf(w.x, v, u0);
            u1 = fmaf(w.y, v, u1);
            u2 = fmaf(w.z, v, u2);
            u3 = fmaf(w.w, v, u3);
        }
        u0 = fmaxf(u0, 0.0f);  // relu(s1*conv1 + t1)
        u1 = fmaxf(u1, 0.0f);
        u2 = fmaxf(u2, 0.0f);
        u3 = fmaxf(u3, 0.0f);
        const float uq0 = u0 * q, uq1 = u1 * q, uq2 = u2 * q, uq3 = u3 * q;

        float p[3];
#pragma unroll
        for (int oc = 0; oc < 3; ++oc) {
            p[oc] = A[oc][0] * u0 + A[oc][1] * u1 + A[oc][2] * u2 + A[oc][3] * u3
                  + Bq[oc][0] * uq0 + Bq[oc][1] * uq1 + Bq[oc][2] * uq2 + Bq[oc][3] * uq3;
        }
#pragma unroll
        for (int m = 1; m < 64; m <<= 1) {
            p[0] += __shfl_xor(p[0], m);
            p[1] += __shfl_xor(p[1], m);
            p[2] += __shfl_xor(p[2], m);
        }
        if (lane == 0) {
            zout[((b * 3 + 0) * 64 + hb) * 64 + wb] = p[0] + zc0;
            zout[((b * 3 + 1) * 64 + hb) * 64 + wb] = p[1] + zc1;
            zout[((b * 3 + 2) * 64 + hb) * 64 + wb] = p[2] + zc2;
        }
    }
}

// Bilinear x8 upsample, half-pixel centers (align_corners=False), edge clamp.
// src = (dst + 0.5)/8 - 0.5; weights periodic with dst%8.
__global__ __launch_bounds__(256) void upsample8(
    const float* __restrict__ z,   // [8,3,64,64]
    float* __restrict__ out)       // [8,3,512,512]
{
    const int idx = blockIdx.x * 256 + threadIdx.x;   // 1,572,864 threads, 4 outs each
    const int x4    = idx & 127;
    const int rest  = idx >> 7;
    const int yy    = rest & 511;
    const int plane = rest >> 9;          // b*3 + oc, 0..23

    const float* zp = z + plane * 4096;

    const int yb = yy >> 3, r = yy & 7;
    int y0; float fy;
    if (r < 4) { y0 = yb - 1; fy = (2 * r + 9) * (1.0f / 16.0f); }
    else       { y0 = yb;     fy = (2 * r - 7) * (1.0f / 16.0f); }
    int y1 = y0 + 1;
    y0 = y0 < 0 ? 0 : y0;
    y1 = y1 > 63 ? 63 : y1;
    const float* row0 = zp + y0 * 64;
    const float* row1 = zp + y1 * 64;

    float4 res;
    float* rp = (float*)&res;
#pragma unroll
    for (int t = 0; t < 4; ++t) {
        int x = x4 * 4 + t;
        int xb = x >> 3, rr = x & 7;
        int x0; float fx;
        if (rr < 4) { x0 = xb - 1; fx = (2 * rr + 9) * (1.0f / 16.0f); }
        else        { x0 = xb;     fx = (2 * rr - 7) * (1.0f / 16.0f); }
        int x1 = x0 + 1;
        x0 = x0 < 0 ? 0 : x0;
        x1 = x1 > 63 ? 63 : x1;
        float a0 = row0[x0], a1 = row0[x1];
        float b0v = row1[x0], b1v = row1[x1];
        float v0 = a0 + fx * (a1 - a0);
        float v1 = b0v + fx * (b1v - b0v);
        rp[t] = v0 + fy * (v1 - v0);
    }
    *(float4*)&out[idx * 4] = res;
}

extern "C" void kernel_launch(void* const* d_in, const int* in_sizes, int n_in,
                              void* d_out, int out_size, void* d_ws, size_t ws_size,
                              hipStream_t stream) {
    const int*   x      = (const int*)d_in[0];
    const float* qtable = (const float*)d_in[1];
    const float* w0     = (const float*)d_in[2];
    const float* b0     = (const float*)d_in[3];
    const float* s0     = (const float*)d_in[4];
    const float* t0     = (const float*)d_in[5];
    const float* w1     = (const float*)d_in[6];
    const float* s1     = (const float*)d_in[7];
    const float* t1     = (const float*)d_in[8];
    const float* w2     = (const float*)d_in[9];
    const float* b2     = (const float*)d_in[10];
    const float* s2     = (const float*)d_in[11];
    const float* t2     = (const float*)d_in[12];

    float* zbuf = (float*)d_ws;            // needs 8*3*64*64*4 = 393,216 B
    float* out  = (float*)d_out;

    dct_stage1<<<2048, 256, 0, stream>>>(x, qtable, w0, b0, s0, t0,
                                         w1, s1, t1, w2, b2, s2, t2, zbuf);
    upsample8<<<6144, 256, 0, stream>>>(zbuf, out);
}

// Round 3
// 114.803 us; speedup vs baseline: 3.5480x; 3.5480x over previous
//
#include <hip/hip_runtime.h>

// Pipeline (see reference):
//   bins = clip(|x|,0,20)  -> one-hot conv == per-pixel gather of w0[o, bin(tap), k]
//   stage0 kernel: build folded table tab[k][bin][o] (+ sentinel bin 21) in d_ws
//   stage1 kernel: fused layer0 (dil-8 3x3, BN0 folded) + layer1 (1x1 64->4, s1 folded
//                  OUTSIDE the o-loop -> w1 read via scalar loads) + block rearrange
//                  (x qtable) + 1x1 512->3 (+b2, BN2 folded) -> z [8,3,64,64] in d_ws
//   stage2 kernel: bilinear x8 upsample (half-pixel centers, edge clamp) -> d_out
//
// R3 (fix of R2's scratch-spill regression: full unroll + pointer array caused
// 731MB/345MB scratch traffic):
//   - o-loop partial unroll (4 pair-iters), 9 NAMED tap base pointers (SSA scalars)
//   - pairwise reads tab[e], tab[e+1] -> ds_read2_b32 (2 dwords/instr, halves LDS
//     instruction count vs R1; stride 65 is odd so b64 can't be formed -> safe)
//   - stride 65 == 1 (mod 32): distinct bins -> distinct banks; dup bins -> broadcast
//   - grid 2048 (3 blocks/CU, LDS-capped), table pre-built once and loaded coalesced

#define NB_BINS 22   // 21 real bins + sentinel bin 21 for out-of-bounds taps
#define OSTRIDE 65   // 64 channels + 1 pad float (bank spread)
#define TAB_N   (9 * NB_BINS * OSTRIDE)

__global__ __launch_bounds__(256) void build_tab(
    const float* __restrict__ w0,   // [64,21,3,3]
    const float* __restrict__ b0,
    const float* __restrict__ s0,
    const float* __restrict__ t0,
    float* __restrict__ tabg)       // [9*22*65]
{
    for (int t = threadIdx.x; t < 9 * NB_BINS * 64; t += 256) {
        int kb = t >> 6;              // k*22 + bin
        int o  = t & 63;
        int k   = kb / NB_BINS;
        int bin = kb - k * NB_BINS;
        float g0 = fmaf(s0[o], b0[o], t0[o]) * (1.0f / 9.0f);
        float val = g0;
        if (bin < 21) {
            int ky = k / 3, kx = k - ky * 3;
            val = fmaf(s0[o], w0[((o * 21 + bin) * 3 + ky) * 3 + kx], g0);
        }
        tabg[kb * OSTRIDE + o] = val;
    }
}

template <bool PRE>
__global__ __launch_bounds__(256, 3) void dct_stage1(
    const int* __restrict__ xin,      // [8,1,512,512] int32
    const float* __restrict__ qtable, // [8,8,8]
    const float* __restrict__ w0,     // [64,21,3,3]
    const float* __restrict__ b0,     // [64]
    const float* __restrict__ s0,     // [64]
    const float* __restrict__ t0,     // [64]
    const float* __restrict__ w1,     // [4,64]
    const float* __restrict__ s1,     // [4]
    const float* __restrict__ t1,     // [4]
    const float* __restrict__ w2,     // [3,512]
    const float* __restrict__ b2,     // [3]
    const float* __restrict__ s2,     // [3]
    const float* __restrict__ t2,     // [3]
    const float* __restrict__ tabg,   // prebuilt table (PRE) or nullptr
    float* __restrict__ zout)         // [8,3,64,64]
{
    // tab[k][bin][o] = s0[o]*w0[o][bin][ky][kx] + g0[o]/9   (bin < 21)
    //               = g0[o]/9                               (bin == 21, OOB tap)
    // where g0 = s0*b0 + t0.  Sum over the 9 taps equals s0*conv + g0 exactly.
    __shared__ float tab[TAB_N];   // 51480 B

    const int tid = threadIdx.x;
    const int bid = blockIdx.x;       // 2048 workgroups: (b, hb, seg)
    const int b   = bid >> 8;
    const int hb  = (bid >> 2) & 63;
    const int seg = bid & 3;

    if (PRE) {
        for (int t = tid; t < TAB_N; t += 256) tab[t] = tabg[t];
    } else {
        for (int t = tid; t < 9 * NB_BINS * 64; t += 256) {
            int kb = t >> 6;
            int o  = t & 63;
            int k   = kb / NB_BINS;
            int bin = kb - k * NB_BINS;
            float g0 = fmaf(s0[o], b0[o], t0[o]) * (1.0f / 9.0f);
            float val = g0;
            if (bin < 21) {
                int ky = k / 3, kx = k - ky * 3;
                val = fmaf(s0[o], w0[((o * 21 + bin) * 3 + ky) * 3 + kx], g0);
            }
            tab[kb * OSTRIDE + o] = val;
        }
    }
    __syncthreads();

    const int lane = tid & 63;
    const int wave = tid >> 6;
    const int i = lane >> 3;          // row within 8x8 block
    const int j = lane & 7;           // col within 8x8 block

    // Per-lane constants for the block-rearrange + 512->3 conv.
    // z channel index = c*64 + i*8 + j (= c*64 + lane); channels 256.. get *qtable.
    const float q = qtable[b * 64 + lane];
    float A[3][4], Bq[3][4];
#pragma unroll
    for (int oc = 0; oc < 3; ++oc) {
        float s = s2[oc];
#pragma unroll
        for (int c = 0; c < 4; ++c) {
            A[oc][c]  = s * w2[oc * 512 + c * 64 + lane];
            Bq[oc][c] = s * w2[oc * 512 + 256 + c * 64 + lane];
        }
    }
    const float zc0 = fmaf(s2[0], b2[0], t2[0]);
    const float zc1 = fmaf(s2[1], b2[1], t2[1]);
    const float zc2 = fmaf(s2[2], b2[2], t2[2]);
    const float s1r0 = s1[0], s1r1 = s1[1], s1r2 = s1[2], s1r3 = s1[3];
    const float t1r0 = t1[0], t1r1 = t1[1], t1r2 = t1[2], t1r3 = t1[3];

    const int y = hb * 8 + i;
    const int* xin_b = xin + b * 512 * 512;

    for (int t = 0; t < 4; ++t) {
        const int wb = wave * 16 + seg * 4 + t;   // 4 waves x (4 segs x 4) -> 64 blocks
        const int xc = wb * 8 + j;

        // 9 tap bins -> 9 named LDS row base pointers (SSA scalars, no array!)
        const float *tp0, *tp1, *tp2, *tp3, *tp4, *tp5, *tp6, *tp7, *tp8;
#define TAP(K, DY, DX)                                                      \
        {                                                                   \
            int yy = y + (DY), xx = xc + (DX);                              \
            int bin = 21;                                                   \
            if ((unsigned)yy < 512u && (unsigned)xx < 512u) {               \
                int v = xin_b[yy * 512 + xx];                               \
                v = v < 0 ? -v : v;                                         \
                bin = v > 20 ? 20 : v;                                      \
            }                                                               \
            tp##K = &tab[((K) * NB_BINS + bin) * OSTRIDE];                  \
        }
        TAP(0, -8, -8) TAP(1, -8, 0) TAP(2, -8, 8)
        TAP(3,  0, -8) TAP(4,  0, 0) TAP(5,  0, 8)
        TAP(6,  8, -8) TAP(7,  8, 0) TAP(8,  8, 8)
#undef TAP

        float d0 = 0.f, d1 = 0.f, d2 = 0.f, d3 = 0.f;
#pragma unroll 4
        for (int p = 0; p < 32; ++p) {
            const int e = 2 * p, f = 2 * p + 1;
            float aL = tp0[e] + tp1[e] + tp2[e] + tp3[e] + tp4[e]
                     + tp5[e] + tp6[e] + tp7[e] + tp8[e];
            float aH = tp0[f] + tp1[f] + tp2[f] + tp3[f] + tp4[f]
                     + tp5[f] + tp6[f] + tp7[f] + tp8[f];
            float vL = fmaxf(aL, 0.0f);   // relu(s0*conv0 + s0*b0 + t0)
            float vH = fmaxf(aH, 0.0f);
            // w1 indices are wave-uniform -> scalar loads, no LDS traffic
            d0 = fmaf(w1[0 * 64 + f], vH, fmaf(w1[0 * 64 + e], vL, d0));
            d1 = fmaf(w1[1 * 64 + f], vH, fmaf(w1[1 * 64 + e], vL, d1));
            d2 = fmaf(w1[2 * 64 + f], vH, fmaf(w1[2 * 64 + e], vL, d2));
            d3 = fmaf(w1[3 * 64 + f], vH, fmaf(w1[3 * 64 + e], vL, d3));
        }
        // relu(s1*conv1 + t1) with s1 folded outside the loop
        float u0 = fmaxf(fmaf(s1r0, d0, t1r0), 0.0f);
        float u1 = fmaxf(fmaf(s1r1, d1, t1r1), 0.0f);
        float u2 = fmaxf(fmaf(s1r2, d2, t1r2), 0.0f);
        float u3 = fmaxf(fmaf(s1r3, d3, t1r3), 0.0f);
        const float uq0 = u0 * q, uq1 = u1 * q, uq2 = u2 * q, uq3 = u3 * q;

        float p0, p1, p2;
        p0 = A[0][0] * u0 + A[0][1] * u1 + A[0][2] * u2 + A[0][3] * u3
           + Bq[0][0] * uq0 + Bq[0][1] * uq1 + Bq[0][2] * uq2 + Bq[0][3] * uq3;
        p1 = A[1][0] * u0 + A[1][1] * u1 + A[1][2] * u2 + A[1][3] * u3
           + Bq[1][0] * uq0 + Bq[1][1] * uq1 + Bq[1][2] * uq2 + Bq[1][3] * uq3;
        p2 = A[2][0] * u0 + A[2][1] * u1 + A[2][2] * u2 + A[2][3] * u3
           + Bq[2][0] * uq0 + Bq[2][1] * uq1 + Bq[2][2] * uq2 + Bq[2][3] * uq3;
#pragma unroll
        for (int m = 1; m < 64; m <<= 1) {
            p0 += __shfl_xor(p0, m);
            p1 += __shfl_xor(p1, m);
            p2 += __shfl_xor(p2, m);
        }
        if (lane == 0) {
            zout[((b * 3 + 0) * 64 + hb) * 64 + wb] = p0 + zc0;
            zout[((b * 3 + 1) * 64 + hb) * 64 + wb] = p1 + zc1;
            zout[((b * 3 + 2) * 64 + hb) * 64 + wb] = p2 + zc2;
        }
    }
}

// Bilinear x8 upsample, half-pixel centers (align_corners=False), edge clamp.
// src = (dst + 0.5)/8 - 0.5; weights periodic with dst%8.
__global__ __launch_bounds__(256) void upsample8(
    const float* __restrict__ z,   // [8,3,64,64]
    float* __restrict__ out)       // [8,3,512,512]
{
    const int idx = blockIdx.x * 256 + threadIdx.x;   // 1,572,864 threads, 4 outs each
    const int x4    = idx & 127;
    const int rest  = idx >> 7;
    const int yy    = rest & 511;
    const int plane = rest >> 9;          // b*3 + oc, 0..23

    const float* zp = z + plane * 4096;

    const int yb = yy >> 3, r = yy & 7;
    int y0; float fy;
    if (r < 4) { y0 = yb - 1; fy = (2 * r + 9) * (1.0f / 16.0f); }
    else       { y0 = yb;     fy = (2 * r - 7) * (1.0f / 16.0f); }
    int y1 = y0 + 1;
    y0 = y0 < 0 ? 0 : y0;
    y1 = y1 > 63 ? 63 : y1;
    const float* row0 = zp + y0 * 64;
    const float* row1 = zp + y1 * 64;

    float4 res;
    float* rp = (float*)&res;
#pragma unroll
    for (int t = 0; t < 4; ++t) {
        int x = x4 * 4 + t;
        int xb = x >> 3, rr = x & 7;
        int x0; float fx;
        if (rr < 4) { x0 = xb - 1; fx = (2 * rr + 9) * (1.0f / 16.0f); }
        else        { x0 = xb;     fx = (2 * rr - 7) * (1.0f / 16.0f); }
        int x1 = x0 + 1;
        x0 = x0 < 0 ? 0 : x0;
        x1 = x1 > 63 ? 63 : x1;
        float a0 = row0[x0], a1 = row0[x1];
        float b0v = row1[x0], b1v = row1[x1];
        float v0 = a0 + fx * (a1 - a0);
        float v1 = b0v + fx * (b1v - b0v);
        rp[t] = v0 + fy * (v1 - v0);
    }
    *(float4*)&out[idx * 4] = res;
}

extern "C" void kernel_launch(void* const* d_in, const int* in_sizes, int n_in,
                              void* d_out, int out_size, void* d_ws, size_t ws_size,
                              hipStream_t stream) {
    const int*   x      = (const int*)d_in[0];
    const float* qtable = (const float*)d_in[1];
    const float* w0     = (const float*)d_in[2];
    const float* b0     = (const float*)d_in[3];
    const float* s0     = (const float*)d_in[4];
    const float* t0     = (const float*)d_in[5];
    const float* w1     = (const float*)d_in[6];
    const float* s1     = (const float*)d_in[7];
    const float* t1     = (const float*)d_in[8];
    const float* w2     = (const float*)d_in[9];
    const float* b2     = (const float*)d_in[10];
    const float* s2     = (const float*)d_in[11];
    const float* t2     = (const float*)d_in[12];

    float* zbuf = (float*)d_ws;                     // 8*3*64*64*4 = 393,216 B
    float* tabg = (float*)((char*)d_ws + 393216);   // + 51,480 B
    float* out  = (float*)d_out;

    const bool pre = ws_size >= (size_t)(393216 + TAB_N * 4);
    if (pre) {
        build_tab<<<1, 256, 0, stream>>>(w0, b0, s0, t0, tabg);
        dct_stage1<true><<<2048, 256, 0, stream>>>(x, qtable, w0, b0, s0, t0,
                                                   w1, s1, t1, w2, b2, s2, t2,
                                                   tabg, zbuf);
    } else {
        dct_stage1<false><<<2048, 256, 0, stream>>>(x, qtable, w0, b0, s0, t0,
                                                    w1, s1, t1, w2, b2, s2, t2,
                                                    nullptr, zbuf);
    }
    upsample8<<<6144, 256, 0, stream>>>(zbuf, out);
}

// Round 4
// 94.236 us; speedup vs baseline: 4.3224x; 1.2182x over previous
//
#include <hip/hip_runtime.h>

// Pipeline (see reference):
//   bins = clip(|x|,0,20)  -> one-hot conv == per-pixel gather of w0[o, bin(tap), k]
//   stage0 kernel: build folded fp16 table tab[k][bin][o] (+ sentinel bin 21) in d_ws
//   stage1 kernel: fused layer0 (dil-8 3x3, BN0 folded) + layer1 (1x1 64->4, s1 folded
//                  outside o-loop) + block rearrange (x qtable) + 1x1 512->3 (+b2, BN2)
//                  -> z [8,3,64,64] f32 in d_ws
//   stage2 kernel: bilinear x8 upsample (half-pixel centers, edge clamp) -> d_out
//
// R4: stage1 is LDS-instruction-issue bound (R3: 288 ds_read2 x ~6.5cyc x 128
// tiles/CU ~= 100us = measured). Switch table to FP16:
//   - stride 68 halves (136B): rows 8B-aligned -> ds_read_b64 = 4 channels/instr
//     -> 144 DS instr per 8x8 tile (halved). Banks: (34*bin) mod 32 -> only
//     bins 16 apart collide -> max 2-way (free, m136).
//   - 9-tap sum via v_pk_add_f16 (2 ch/instr) + packed relu, f32 conversion only
//     for the 4-channel w1 FMA stage.
//   - LDS 27KB/block -> 4 blocks/CU; grid 4096; unroll 2 (bounded VGPR, no spill).

#define NB_BINS 22   // 21 real bins + sentinel bin 21 for out-of-bounds taps
#define OSTRIDE 68   // 64 channels + 4 pad halves: 136B rows, 8B aligned
#define TAB_N   (9 * NB_BINS * OSTRIDE)   // halves

typedef _Float16 h2 __attribute__((ext_vector_type(2)));

__device__ inline h2 pkmax0(h2 a) {
    unsigned r, ua = __builtin_bit_cast(unsigned, a);
    asm("v_pk_max_f16 %0, %1, %2" : "=v"(r) : "v"(ua), "v"(0u));
    return __builtin_bit_cast(h2, r);
}
#define H2(u) __builtin_bit_cast(h2, (u))

__global__ __launch_bounds__(256) void build_tab(
    const float* __restrict__ w0,   // [64,21,3,3]
    const float* __restrict__ b0,
    const float* __restrict__ s0,
    const float* __restrict__ t0,
    _Float16* __restrict__ tabg)    // [9*22*68]
{
    for (int t = threadIdx.x; t < 9 * NB_BINS * 64; t += 256) {
        int kb = t >> 6;              // k*22 + bin
        int o  = t & 63;
        int k   = kb / NB_BINS;
        int bin = kb - k * NB_BINS;
        float g0 = fmaf(s0[o], b0[o], t0[o]) * (1.0f / 9.0f);
        float val = g0;
        if (bin < 21) {
            int ky = k / 3, kx = k - ky * 3;
            val = fmaf(s0[o], w0[((o * 21 + bin) * 3 + ky) * 3 + kx], g0);
        }
        tabg[kb * OSTRIDE + o] = (_Float16)val;
    }
}

template <bool PRE>
__global__ __launch_bounds__(256, 4) void dct_stage1(
    const int* __restrict__ xin,      // [8,1,512,512] int32
    const float* __restrict__ qtable, // [8,8,8]
    const float* __restrict__ w0,     // [64,21,3,3]
    const float* __restrict__ b0,     // [64]
    const float* __restrict__ s0,     // [64]
    const float* __restrict__ t0,     // [64]
    const float* __restrict__ w1,     // [4,64]
    const float* __restrict__ s1,     // [4]
    const float* __restrict__ t1,     // [4]
    const float* __restrict__ w2,     // [3,512]
    const float* __restrict__ b2,     // [3]
    const float* __restrict__ s2,     // [3]
    const float* __restrict__ t2,     // [3]
    const _Float16* __restrict__ tabg,
    float* __restrict__ zout)         // [8,3,64,64]
{
    // tab[k][bin][o] = fp16( s0[o]*w0[o][bin][ky][kx] + g0[o]/9 )  (bin < 21)
    //               = fp16( g0[o]/9 )                              (bin == 21, OOB)
    // g0 = s0*b0 + t0.  Sum over 9 taps == s0*conv + g0 (up to fp16 rounding).
    __shared__ _Float16 tab[TAB_N];   // 26,928 B

    const int tid = threadIdx.x;
    const int bid = blockIdx.x;       // 4096 workgroups: (b, hb, seg)
    const int b   = bid >> 9;
    const int hb  = (bid >> 3) & 63;
    const int seg = bid & 7;

    if (PRE) {
        const unsigned* tg = (const unsigned*)tabg;
        unsigned* tl = (unsigned*)tab;
        for (int t = tid; t < TAB_N / 2; t += 256) tl[t] = tg[t];
    } else {
        for (int t = tid; t < 9 * NB_BINS * 64; t += 256) {
            int kb = t >> 6;
            int o  = t & 63;
            int k   = kb / NB_BINS;
            int bin = kb - k * NB_BINS;
            float g0 = fmaf(s0[o], b0[o], t0[o]) * (1.0f / 9.0f);
            float val = g0;
            if (bin < 21) {
                int ky = k / 3, kx = k - ky * 3;
                val = fmaf(s0[o], w0[((o * 21 + bin) * 3 + ky) * 3 + kx], g0);
            }
            tab[kb * OSTRIDE + o] = (_Float16)val;
        }
    }
    __syncthreads();

    const int lane = tid & 63;
    const int wave = tid >> 6;
    const int i = lane >> 3;          // row within 8x8 block
    const int j = lane & 7;           // col within 8x8 block

    // Per-lane constants for the block-rearrange + 512->3 conv.
    // z channel index = c*64 + i*8 + j (= c*64 + lane); channels 256.. get *qtable.
    const float q = qtable[b * 64 + lane];
    float A[3][4], Bq[3][4];
#pragma unroll
    for (int oc = 0; oc < 3; ++oc) {
        float s = s2[oc];
#pragma unroll
        for (int c = 0; c < 4; ++c) {
            A[oc][c]  = s * w2[oc * 512 + c * 64 + lane];
            Bq[oc][c] = s * w2[oc * 512 + 256 + c * 64 + lane];
        }
    }
    const float zc0 = fmaf(s2[0], b2[0], t2[0]);
    const float zc1 = fmaf(s2[1], b2[1], t2[1]);
    const float zc2 = fmaf(s2[2], b2[2], t2[2]);
    const float s1r0 = s1[0], s1r1 = s1[1], s1r2 = s1[2], s1r3 = s1[3];
    const float t1r0 = t1[0], t1r1 = t1[1], t1r2 = t1[2], t1r3 = t1[3];

    const int y = hb * 8 + i;
    const int* xin_b = xin + b * 512 * 512;

    for (int t = 0; t < 2; ++t) {
        const int wb = wave * 16 + seg * 2 + t;   // 4 waves x 8 segs x 2 -> 64 blocks
        const int xc = wb * 8 + j;

        // 9 tap bins -> 9 named LDS row base pointers (SSA scalars, no array!)
        const _Float16 *tp0, *tp1, *tp2, *tp3, *tp4, *tp5, *tp6, *tp7, *tp8;
#define TAP(K, DY, DX)                                                      \
        {                                                                   \
            int yy = y + (DY), xx = xc + (DX);                              \
            int bin = 21;                                                   \
            if ((unsigned)yy < 512u && (unsigned)xx < 512u) {               \
                int v = xin_b[yy * 512 + xx];                               \
                v = v < 0 ? -v : v;                                         \
                bin = v > 20 ? 20 : v;                                      \
            }                                                               \
            tp##K = &tab[((K) * NB_BINS + bin) * OSTRIDE];                  \
        }
        TAP(0, -8, -8) TAP(1, -8, 0) TAP(2, -8, 8)
        TAP(3,  0, -8) TAP(4,  0, 0) TAP(5,  0, 8)
        TAP(6,  8, -8) TAP(7,  8, 0) TAP(8,  8, 8)
#undef TAP

        float d0 = 0.f, d1 = 0.f, d2 = 0.f, d3 = 0.f;
#pragma unroll 2
        for (int c4 = 0; c4 < 16; ++c4) {
            const int e = c4 * 4;     // first channel of this quad
            // 9 x ds_read_b64: 4 fp16 channels per tap
            uint2 q0 = *(const uint2*)(tp0 + e);
            uint2 q1 = *(const uint2*)(tp1 + e);
            uint2 q2 = *(const uint2*)(tp2 + e);
            uint2 q3 = *(const uint2*)(tp3 + e);
            uint2 q4 = *(const uint2*)(tp4 + e);
            uint2 q5 = *(const uint2*)(tp5 + e);
            uint2 q6 = *(const uint2*)(tp6 + e);
            uint2 q7 = *(const uint2*)(tp7 + e);
            uint2 q8 = *(const uint2*)(tp8 + e);
            h2 aL = ((H2(q0.x) + H2(q1.x)) + (H2(q2.x) + H2(q3.x)))
                  + ((H2(q4.x) + H2(q5.x)) + (H2(q6.x) + H2(q7.x))) + H2(q8.x);
            h2 aH = ((H2(q0.y) + H2(q1.y)) + (H2(q2.y) + H2(q3.y)))
                  + ((H2(q4.y) + H2(q5.y)) + (H2(q6.y) + H2(q7.y))) + H2(q8.y);
            aL = pkmax0(aL);          // relu(s0*conv0 + s0*b0 + t0), packed
            aH = pkmax0(aH);
            float v0 = (float)aL.x, v1 = (float)aL.y;
            float v2 = (float)aH.x, v3 = (float)aH.y;
            // w1 indices are wave-uniform -> scalar loads, no LDS traffic
            d0 = fmaf(w1[0*64+e+3], v3, fmaf(w1[0*64+e+2], v2,
                 fmaf(w1[0*64+e+1], v1, fmaf(w1[0*64+e+0], v0, d0))));
            d1 = fmaf(w1[1*64+e+3], v3, fmaf(w1[1*64+e+2], v2,
                 fmaf(w1[1*64+e+1], v1, fmaf(w1[1*64+e+0], v0, d1))));
            d2 = fmaf(w1[2*64+e+3], v3, fmaf(w1[2*64+e+2], v2,
                 fmaf(w1[2*64+e+1], v1, fmaf(w1[2*64+e+0], v0, d2))));
            d3 = fmaf(w1[3*64+e+3], v3, fmaf(w1[3*64+e+2], v2,
                 fmaf(w1[3*64+e+1], v1, fmaf(w1[3*64+e+0], v0, d3))));
        }
        // relu(s1*conv1 + t1) with s1 folded outside the loop
        float u0 = fmaxf(fmaf(s1r0, d0, t1r0), 0.0f);
        float u1 = fmaxf(fmaf(s1r1, d1, t1r1), 0.0f);
        float u2 = fmaxf(fmaf(s1r2, d2, t1r2), 0.0f);
        float u3 = fmaxf(fmaf(s1r3, d3, t1r3), 0.0f);
        const float uq0 = u0 * q, uq1 = u1 * q, uq2 = u2 * q, uq3 = u3 * q;

        float p0, p1, p2;
        p0 = A[0][0] * u0 + A[0][1] * u1 + A[0][2] * u2 + A[0][3] * u3
           + Bq[0][0] * uq0 + Bq[0][1] * uq1 + Bq[0][2] * uq2 + Bq[0][3] * uq3;
        p1 = A[1][0] * u0 + A[1][1] * u1 + A[1][2] * u2 + A[1][3] * u3
           + Bq[1][0] * uq0 + Bq[1][1] * uq1 + Bq[1][2] * uq2 + Bq[1][3] * uq3;
        p2 = A[2][0] * u0 + A[2][1] * u1 + A[2][2] * u2 + A[2][3] * u3
           + Bq[2][0] * uq0 + Bq[2][1] * uq1 + Bq[2][2] * uq2 + Bq[2][3] * uq3;
#pragma unroll
        for (int m = 1; m < 64; m <<= 1) {
            p0 += __shfl_xor(p0, m);
            p1 += __shfl_xor(p1, m);
            p2 += __shfl_xor(p2, m);
        }
        if (lane == 0) {
            zout[((b * 3 + 0) * 64 + hb) * 64 + wb] = p0 + zc0;
            zout[((b * 3 + 1) * 64 + hb) * 64 + wb] = p1 + zc1;
            zout[((b * 3 + 2) * 64 + hb) * 64 + wb] = p2 + zc2;
        }
    }
}

// Bilinear x8 upsample, half-pixel centers (align_corners=False), edge clamp.
// src = (dst + 0.5)/8 - 0.5; weights periodic with dst%8.
__global__ __launch_bounds__(256) void upsample8(
    const float* __restrict__ z,   // [8,3,64,64]
    float* __restrict__ out)       // [8,3,512,512]
{
    const int idx = blockIdx.x * 256 + threadIdx.x;   // 1,572,864 threads, 4 outs each
    const int x4    = idx & 127;
    const int rest  = idx >> 7;
    const int yy    = rest & 511;
    const int plane = rest >> 9;          // b*3 + oc, 0..23

    const float* zp = z + plane * 4096;

    const int yb = yy >> 3, r = yy & 7;
    int y0; float fy;
    if (r < 4) { y0 = yb - 1; fy = (2 * r + 9) * (1.0f / 16.0f); }
    else       { y0 = yb;     fy = (2 * r - 7) * (1.0f / 16.0f); }
    int y1 = y0 + 1;
    y0 = y0 < 0 ? 0 : y0;
    y1 = y1 > 63 ? 63 : y1;
    const float* row0 = zp + y0 * 64;
    const float* row1 = zp + y1 * 64;

    float4 res;
    float* rp = (float*)&res;
#pragma unroll
    for (int t = 0; t < 4; ++t) {
        int x = x4 * 4 + t;
        int xb = x >> 3, rr = x & 7;
        int x0; float fx;
        if (rr < 4) { x0 = xb - 1; fx = (2 * rr + 9) * (1.0f / 16.0f); }
        else        { x0 = xb;     fx = (2 * rr - 7) * (1.0f / 16.0f); }
        int x1 = x0 + 1;
        x0 = x0 < 0 ? 0 : x0;
        x1 = x1 > 63 ? 63 : x1;
        float a0 = row0[x0], a1 = row0[x1];
        float b0v = row1[x0], b1v = row1[x1];
        float v0 = a0 + fx * (a1 - a0);
        float v1 = b0v + fx * (b1v - b0v);
        rp[t] = v0 + fy * (v1 - v0);
    }
    *(float4*)&out[idx * 4] = res;
}

extern "C" void kernel_launch(void* const* d_in, const int* in_sizes, int n_in,
                              void* d_out, int out_size, void* d_ws, size_t ws_size,
                              hipStream_t stream) {
    const int*   x      = (const int*)d_in[0];
    const float* qtable = (const float*)d_in[1];
    const float* w0     = (const float*)d_in[2];
    const float* b0     = (const float*)d_in[3];
    const float* s0     = (const float*)d_in[4];
    const float* t0     = (const float*)d_in[5];
    const float* w1     = (const float*)d_in[6];
    const float* s1     = (const float*)d_in[7];
    const float* t1     = (const float*)d_in[8];
    const float* w2     = (const float*)d_in[9];
    const float* b2     = (const float*)d_in[10];
    const float* s2     = (const float*)d_in[11];
    const float* t2     = (const float*)d_in[12];

    float*    zbuf = (float*)d_ws;                       // 393,216 B
    _Float16* tabg = (_Float16*)((char*)d_ws + 393216);  // + 26,928 B
    float*    out  = (float*)d_out;

    const bool pre = ws_size >= (size_t)(393216 + TAB_N * 2);
    if (pre) {
        build_tab<<<1, 256, 0, stream>>>(w0, b0, s0, t0, tabg);
        dct_stage1<true><<<4096, 256, 0, stream>>>(x, qtable, w0, b0, s0, t0,
                                                   w1, s1, t1, w2, b2, s2, t2,
                                                   tabg, zbuf);
    } else {
        dct_stage1<false><<<4096, 256, 0, stream>>>(x, qtable, w0, b0, s0, t0,
                                                    w1, s1, t1, w2, b2, s2, t2,
                                                    nullptr, zbuf);
    }
    upsample8<<<6144, 256, 0, stream>>>(zbuf, out);
}